// Round 1
// baseline (86.332 us; speedup 1.0000x reference)
//
#include <hip/hip_runtime.h>

// Problem constants (from reference): B=16, T=2048, F=32, D=128.
// Key identity: softmax over a singleton axis == 1.0, so the GRN branch is
// dead and z = x @ Wp + colsum_f(bp); w = ones(B,T,F,1).

#define BB 16
#define TT 2048
#define FF 32
#define DD 128

constexpr int ROWS = BB * TT;            // 32768
constexpr int BLOCK = 256;
constexpr int ROWS_PER_BLOCK = 8;        // 8 rows x 128 d = 1024 outputs/block
constexpr int NBLOCKS = ROWS / ROWS_PER_BLOCK;  // 4096
constexpr int W_ELEMS = ROWS * FF;       // 1048576 floats of 1.0
constexpr int W_F4_PER_BLOCK = (W_ELEMS / 4) / NBLOCKS;  // 64 float4 per block

__global__ __launch_bounds__(BLOCK) void vsn_kernel(
    const float* __restrict__ x,    // (ROWS, F)
    const float* __restrict__ Wp,   // (F, D)
    const float* __restrict__ bp,   // (F, D)
    float* __restrict__ z,          // (ROWS, D)
    float* __restrict__ w)          // (ROWS*F) -> all ones
{
    __shared__ float wp_s[FF * DD];              // 16 KiB
    __shared__ float bsum_s[DD];
    __shared__ float x_s[ROWS_PER_BLOCK][FF];    // 1 KiB

    const int tid = threadIdx.x;

    // Stage Wp (4096 floats = 1024 float4; 4 per thread), coalesced.
    const float4* wp4g = (const float4*)Wp;
    float4* wp4s = (float4*)wp_s;
#pragma unroll
    for (int i = 0; i < (FF * DD / 4) / BLOCK; ++i)
        wp4s[tid + i * BLOCK] = wp4g[tid + i * BLOCK];

    // Column-sum of bp: thread d sums over f (coalesced across threads).
    if (tid < DD) {
        float s = 0.f;
#pragma unroll
        for (int f = 0; f < FF; ++f) s += bp[f * DD + tid];
        bsum_s[tid] = s;
    }

    // Stage 8 x-rows (256 floats, one per thread, fully coalesced).
    const int row0 = blockIdx.x * ROWS_PER_BLOCK;
    x_s[tid >> 5][tid & 31] = x[row0 * FF + tid];

    __syncthreads();

    const int lane_d = tid & 31;   // which float4 of the 128-wide d dim
    const int rloc   = tid >> 5;   // local row 0..7
    const float4* wpq = (const float4*)wp_s;       // [F][32] float4 view
    float4 acc = ((const float4*)bsum_s)[lane_d];  // init with bias colsum

#pragma unroll
    for (int f = 0; f < FF; ++f) {
        const float  xv = x_s[rloc][f];            // wave-uniform-ish broadcast
        const float4 wv = wpq[f * 32 + lane_d];    // conflict-free (2-way max)
        acc.x = fmaf(xv, wv.x, acc.x);
        acc.y = fmaf(xv, wv.y, acc.y);
        acc.z = fmaf(xv, wv.z, acc.z);
        acc.w = fmaf(xv, wv.w, acc.w);
    }

    ((float4*)z)[(size_t)(row0 + rloc) * 32 + lane_d] = acc;  // coalesced 16B

    // Fill this block's slice of w with ones (64 float4 = 1 KiB per block).
    if (tid < W_F4_PER_BLOCK) {
        ((float4*)w)[(size_t)blockIdx.x * W_F4_PER_BLOCK + tid] =
            make_float4(1.f, 1.f, 1.f, 1.f);
    }
}

extern "C" void kernel_launch(void* const* d_in, const int* in_sizes, int n_in,
                              void* d_out, int out_size, void* d_ws, size_t ws_size,
                              hipStream_t stream) {
    const float* x  = (const float*)d_in[0];
    const float* Wp = (const float*)d_in[1];
    const float* bp = (const float*)d_in[2];
    // Outputs concatenated flat in return order: z (B,T,D) then w (B,T,F,1).
    float* z = (float*)d_out;
    float* w = (float*)d_out + (size_t)ROWS * DD;

    vsn_kernel<<<NBLOCKS, BLOCK, 0, stream>>>(x, Wp, bp, z, w);
}